// Round 9
// baseline (288.466 us; speedup 1.0000x reference)
//
#include <hip/hip_runtime.h>
#include <hip/hip_fp16.h>
#include <math.h>

// ---------------------------------------------------------------------------
// GAT 2-layer forward, N=50000, E=800000 (+N self loops), EMB=128,
// layer1: heads=8, C=16 (concat -> 128), layer2: heads=1, C=64.
// CSR-by-dst build per call, one gather pass per layer, softmax without
// max-subtraction. h1/h2/act1 fp16.
// R9: GEMMs moved to MFMA (v_mfma_f32_16x16x32_f16, fp32 accum). Alpha dots
//     folded in as augmented weight columns: W1aug=[W1|W1 a1s|W1 a1d] (144c),
//     W2aug=[W2|W2 a2s|W2 a2d] (80c, padded), stored TRANSPOSED fp16 by a tiny
//     2-block prep kernel -> B-frags are contiguous 16B loads (L1-resident).
//     gemm2 reads act1 (fp16) directly from global: zero LDS.
// ---------------------------------------------------------------------------

typedef _Float16 f16x8 __attribute__((ext_vector_type(8)));
typedef float f32x4 __attribute__((ext_vector_type(4)));

__global__ __launch_bounds__(256) void scan1_kernel(const int* __restrict__ deg, int N,
                                                    int* __restrict__ rowstart,
                                                    int* __restrict__ blocksum) {
    __shared__ int tmp[256];
    int t = threadIdx.x;
    int i = blockIdx.x * 256 + t;
    int v = (i < N) ? deg[i] : 0;
    tmp[t] = v;
    __syncthreads();
    for (int off = 1; off < 256; off <<= 1) {
        int x = (t >= off) ? tmp[t - off] : 0;
        __syncthreads();
        tmp[t] += x;
        __syncthreads();
    }
    if (i < N) rowstart[i] = tmp[t] - v;
    if (t == 255) blocksum[blockIdx.x] = tmp[t];
}

__global__ __launch_bounds__(256) void scan23_kernel(int* __restrict__ rowstart,
                                                     const int* __restrict__ blocksum,
                                                     int nb,
                                                     int* __restrict__ cursor,
                                                     int N, int E) {
    __shared__ int sdata[256];
    int t = threadIdx.x;
    int b = blockIdx.x;
    sdata[t] = (t < nb && t < b) ? blocksum[t] : 0;
    __syncthreads();
#pragma unroll
    for (int off = 128; off > 0; off >>= 1) {
        if (t < off) sdata[t] += sdata[t + off];
        __syncthreads();
    }
    int offset = sdata[0];
    int i = b * 256 + t;
    if (i < N) {
        int v = rowstart[i] + offset;
        rowstart[i] = v;
        cursor[i] = v;
    } else if (i == N) {
        rowstart[N] = E;
    }
}

__global__ __launch_bounds__(256) void scatter_kernel(const int* __restrict__ src,
                                                      const int* __restrict__ dst,
                                                      int E, int N,
                                                      int* __restrict__ cursor,
                                                      int* __restrict__ esrc) {
    int b = blockIdx.x & 7;
    int chunk = blockIdx.x >> 3;
    int bdiv = (N + 7) >> 3;
    int blo = b * bdiv;
    int bhi = blo + bdiv;
    int base = chunk * 1024 + threadIdx.x;
#pragma unroll
    for (int u = 0; u < 4; u++) {
        int i = base + u * 256;
        if (i < E) {
            int d = dst[i];
            int s = src[i];
            if (d >= blo && d < bhi) {
                int p = atomicAdd(&cursor[d], 1);
                esrc[p] = s;
            }
        }
    }
}

// Prep: build transposed fp16 augmented weights.
// block 0: W1t[144][128]: c<128 -> W1[k][c]; c=128+h -> sum_j W1[k][16h+j]*a1s[h][j];
//          c=136+h -> same with a1d.
// block 1: W2t[80][128]: c<64 -> W2[k][c]; c=64 -> W2[k][:].a2s; c=65 -> .a2d; else 0.
__global__ __launch_bounds__(256) void augw_kernel(const float* __restrict__ W1,
                                                   const float* __restrict__ a1s,
                                                   const float* __restrict__ a1d,
                                                   const float* __restrict__ W2,
                                                   const float* __restrict__ a2s,
                                                   const float* __restrict__ a2d,
                                                   _Float16* __restrict__ W1t,
                                                   _Float16* __restrict__ W2t) {
    int t = threadIdx.x;
    if (blockIdx.x == 0) {
        for (int i = t; i < 144 * 128; i += 256) {
            int c = i >> 7, k = i & 127;
            float v;
            if (c < 128) {
                v = W1[k * 128 + c];
            } else if (c < 136) {
                int h = c - 128; v = 0.f;
#pragma unroll
                for (int j = 0; j < 16; j++) v += W1[k * 128 + h * 16 + j] * a1s[h * 16 + j];
            } else {
                int h = c - 136; v = 0.f;
#pragma unroll
                for (int j = 0; j < 16; j++) v += W1[k * 128 + h * 16 + j] * a1d[h * 16 + j];
            }
            W1t[c * 128 + k] = (_Float16)v;
        }
    } else {
        for (int i = t; i < 80 * 128; i += 256) {
            int c = i >> 7, k = i & 127;
            float v = 0.f;
            if (c < 64) {
                v = W2[k * 64 + c];
            } else if (c == 64) {
                for (int j = 0; j < 64; j++) v += W2[k * 64 + j] * a2s[j];
            } else if (c == 65) {
                for (int j = 0; j < 64; j++) v += W2[k * 64 + j] * a2d[j];
            }
            W2t[c * 128 + k] = (_Float16)v;
        }
    }
}

// Fat kernel: blocks [0,GH) = edge histogram; blocks [GH,GH+G1) = MFMA GEMM1.
// GEMM1: 64 rows x 144 cols per block (4 waves x 16 rows, 9 col-frags).
// x staged fp32->fp16 into LDS (stride 136 halves, conflict-free); W1t B-frags
// read from global (36KB, L1-resident). D layout: row=quad*4+r, col=lane&15.
__global__ __launch_bounds__(256) void gemm1_hist_kernel(const float* __restrict__ x,
                                                         const _Float16* __restrict__ W1t,
                                                         __half* __restrict__ h1,
                                                         float* __restrict__ als,
                                                         float* __restrict__ ald, int N,
                                                         const int* __restrict__ dst,
                                                         int E, int* __restrict__ deg,
                                                         int GH) {
    if ((int)blockIdx.x < GH) {  // ---- histogram ----
        int i = (blockIdx.x * 256 + threadIdx.x) * 4;
        if (i + 3 < E) {
            int4 d = *(const int4*)(dst + i);
            atomicAdd(&deg[d.x], 1);
            atomicAdd(&deg[d.y], 1);
            atomicAdd(&deg[d.z], 1);
            atomicAdd(&deg[d.w], 1);
        } else {
            for (int k = i; k < E; k++) atomicAdd(&deg[dst[k]], 1);
        }
        return;
    }
    __shared__ _Float16 Xs[64 * 136];  // 17 KB
    int t = threadIdx.x;
    int row0 = ((int)blockIdx.x - GH) * 64;
    // stage x tile (64 rows x 128 k) fp32 -> fp16
    for (int i = t; i < 2048; i += 256) {
        int r = i >> 5, c4 = i & 31;
        int gr = row0 + r;
        float4 v = make_float4(0.f, 0.f, 0.f, 0.f);
        if (gr < N) v = *(const float4*)(x + (size_t)gr * 128 + c4 * 4);
        _Float16* dp = Xs + r * 136 + c4 * 4;
        dp[0] = (_Float16)v.x; dp[1] = (_Float16)v.y;
        dp[2] = (_Float16)v.z; dp[3] = (_Float16)v.w;
    }
    __syncthreads();
    int w = t >> 6, L = t & 63, m = L & 15, quad = L >> 4;
    f32x4 acc[9];
#pragma unroll
    for (int f = 0; f < 9; f++) acc[f] = (f32x4){0.f, 0.f, 0.f, 0.f};
    const _Float16* Arow = Xs + (w * 16 + m) * 136 + quad * 8;
    const _Float16* Brow = W1t + m * 128 + quad * 8;
#pragma unroll
    for (int kt = 0; kt < 4; kt++) {
        f16x8 a = *(const f16x8*)(Arow + kt * 32);
#pragma unroll
        for (int f = 0; f < 9; f++) {
            f16x8 b = *(const f16x8*)(Brow + f * 2048 + kt * 32);
            acc[f] = __builtin_amdgcn_mfma_f32_16x16x32_f16(a, b, acc[f], 0, 0, 0);
        }
    }
    int nbase = row0 + w * 16 + quad * 4;
#pragma unroll
    for (int r = 0; r < 4; r++) {
        int n = nbase + r;
        if (n < N) {
            __half* hrow = h1 + (size_t)n * 128 + m;
#pragma unroll
            for (int f = 0; f < 8; f++) hrow[f * 16] = __float2half(acc[f][r]);
            float v = acc[8][r];
            if (m < 8) als[n * 8 + m] = v;
            else ald[n * 8 + (m - 8)] = v;
        }
    }
}

// Aggregation layer 1, node-per-group: wave = 8 nodes x 8 lanes; lane q owns
// head q's 16 channels; walks its node's edge list privately (no reduction).
__global__ __launch_bounds__(256) void agg1_kernel(const __half* __restrict__ h1,
                                                   const float* __restrict__ als,
                                                   const float* __restrict__ ald,
                                                   const int* __restrict__ rowstart,
                                                   const int* __restrict__ esrc,
                                                   const float* __restrict__ b1,
                                                   __half* __restrict__ act1, int N) {
    int t = threadIdx.x;
    int lane = t & 63;
    int grp = lane >> 3;
    int q = lane & 7;
    int n = blockIdx.x * 32 + (t >> 6) * 8 + grp;
    if (n >= N) return;
    const float4* h1v = (const float4*)h1;
    float adv = ald[n * 8 + q];
    float acc[16];
    float wsum;
    {  // self loop
        float e = als[n * 8 + q] + adv;
        e = (e > 0.f) ? e : 0.2f * e;
        float w = __expf(e);
        wsum = w;
        float4 hv0 = h1v[(size_t)n * 16 + 2 * q];
        float4 hv1 = h1v[(size_t)n * 16 + 2 * q + 1];
        const __half2* p0 = (const __half2*)&hv0;
        const __half2* p1 = (const __half2*)&hv1;
#pragma unroll
        for (int k = 0; k < 4; k++) {
            float2 f = __half22float2(p0[k]);
            acc[2 * k] = w * f.x;
            acc[2 * k + 1] = w * f.y;
        }
#pragma unroll
        for (int k = 0; k < 4; k++) {
            float2 f = __half22float2(p1[k]);
            acc[8 + 2 * k] = w * f.x;
            acc[8 + 2 * k + 1] = w * f.y;
        }
    }
    int beg = rowstart[n], end = rowstart[n + 1];
    for (int j = beg; j < end; j++) {
        int s = esrc[j];
        float e = als[s * 8 + q] + adv;
        e = (e > 0.f) ? e : 0.2f * e;
        float w = __expf(e);
        wsum += w;
        float4 hv0 = h1v[(size_t)s * 16 + 2 * q];
        float4 hv1 = h1v[(size_t)s * 16 + 2 * q + 1];
        const __half2* p0 = (const __half2*)&hv0;
        const __half2* p1 = (const __half2*)&hv1;
#pragma unroll
        for (int k = 0; k < 4; k++) {
            float2 f = __half22float2(p0[k]);
            acc[2 * k] += w * f.x;
            acc[2 * k + 1] += w * f.y;
        }
#pragma unroll
        for (int k = 0; k < 4; k++) {
            float2 f = __half22float2(p1[k]);
            acc[8 + 2 * k] += w * f.x;
            acc[8 + 2 * k + 1] += w * f.y;
        }
    }
    float inv = 1.f / (wsum + 1e-16f);
    const float* bf = b1 + q * 16;
    __align__(16) __half2 po[8];
#pragma unroll
    for (int k = 0; k < 8; k++) {
        float o0 = acc[2 * k] * inv + bf[2 * k];
        float o1 = acc[2 * k + 1] * inv + bf[2 * k + 1];
        o0 = (o0 > 0.f) ? o0 : (__expf(o0) - 1.f);  // ELU
        o1 = (o1 > 0.f) ? o1 : (__expf(o1) - 1.f);
        po[k] = __floats2half2_rn(o0, o1);
    }
    float4* ov = (float4*)(act1 + (size_t)n * 128 + q * 16);
    ov[0] = ((float4*)po)[0];
    ov[1] = ((float4*)po)[1];
}

// MFMA GEMM2: 64 rows x 80 cols per block; A-frags straight from global act1
// (fp16), B-frags from W2t (20KB, L1-resident). No LDS.
__global__ __launch_bounds__(256) void gemm2_kernel(const __half* __restrict__ act1,
                                                    const _Float16* __restrict__ W2t,
                                                    __half* __restrict__ h2,
                                                    float* __restrict__ al2s,
                                                    float* __restrict__ al2d, int N) {
    int t = threadIdx.x;
    int row0 = blockIdx.x * 64;
    int w = t >> 6, L = t & 63, m = L & 15, quad = L >> 4;
    f32x4 acc[5];
#pragma unroll
    for (int f = 0; f < 5; f++) acc[f] = (f32x4){0.f, 0.f, 0.f, 0.f};
    const _Float16* Arow =
        (const _Float16*)act1 + (size_t)(row0 + w * 16 + m) * 128 + quad * 8;
    const _Float16* Brow = W2t + m * 128 + quad * 8;
#pragma unroll
    for (int kt = 0; kt < 4; kt++) {
        f16x8 a = *(const f16x8*)(Arow + kt * 32);
#pragma unroll
        for (int f = 0; f < 5; f++) {
            f16x8 b = *(const f16x8*)(Brow + f * 2048 + kt * 32);
            acc[f] = __builtin_amdgcn_mfma_f32_16x16x32_f16(a, b, acc[f], 0, 0, 0);
        }
    }
    int nbase = row0 + w * 16 + quad * 4;
#pragma unroll
    for (int r = 0; r < 4; r++) {
        int n = nbase + r;
        if (n < N) {
            __half* hrow = h2 + (size_t)n * 64 + m;
#pragma unroll
            for (int f = 0; f < 4; f++) hrow[f * 16] = __float2half(acc[f][r]);
            if (m == 0) al2s[n] = acc[4][r];
            else if (m == 1) al2d[n] = acc[4][r];
        }
    }
}

// Aggregation layer 2, node-per-group: wave = 8 nodes x 8 lanes; lane q owns
// channels 8q..8q+7; walks its node's edge list privately.
__global__ __launch_bounds__(256) void agg2_kernel(const __half* __restrict__ h2,
                                                   const float* __restrict__ al2s,
                                                   const float* __restrict__ al2d,
                                                   const int* __restrict__ rowstart,
                                                   const int* __restrict__ esrc,
                                                   const float* __restrict__ b2,
                                                   float* __restrict__ out, int N) {
    int t = threadIdx.x;
    int lane = t & 63;
    int grp = lane >> 3;
    int q = lane & 7;
    int n = blockIdx.x * 32 + (t >> 6) * 8 + grp;
    if (n >= N) return;
    const float4* h2v = (const float4*)h2;
    float adv = al2d[n];
    float acc[8];
    float wsum;
    {  // self loop
        float e = al2s[n] + adv;
        e = (e > 0.f) ? e : 0.2f * e;
        float w = __expf(e);
        wsum = w;
        float4 hv = h2v[(size_t)n * 8 + q];
        const __half2* hp = (const __half2*)&hv;
#pragma unroll
        for (int k = 0; k < 4; k++) {
            float2 f = __half22float2(hp[k]);
            acc[2 * k] = w * f.x;
            acc[2 * k + 1] = w * f.y;
        }
    }
    int beg = rowstart[n], end = rowstart[n + 1];
    for (int j = beg; j < end; j++) {
        int s = esrc[j];
        float e = al2s[s] + adv;
        e = (e > 0.f) ? e : 0.2f * e;
        float w = __expf(e);
        wsum += w;
        float4 hv = h2v[(size_t)s * 8 + q];
        const __half2* hp = (const __half2*)&hv;
#pragma unroll
        for (int k = 0; k < 4; k++) {
            float2 f = __half22float2(hp[k]);
            acc[2 * k] += w * f.x;
            acc[2 * k + 1] += w * f.y;
        }
    }
    float inv = 1.f / (wsum + 1e-16f);
    const float* bf = b2 + q * 8;
    float4* ov = (float4*)(out + (size_t)n * 64 + q * 8);
    ov[0] = make_float4(acc[0] * inv + bf[0], acc[1] * inv + bf[1],
                        acc[2] * inv + bf[2], acc[3] * inv + bf[3]);
    ov[1] = make_float4(acc[4] * inv + bf[4], acc[5] * inv + bf[5],
                        acc[6] * inv + bf[6], acc[7] * inv + bf[7]);
}

extern "C" void kernel_launch(void* const* d_in, const int* in_sizes, int n_in,
                              void* d_out, int out_size, void* d_ws, size_t ws_size,
                              hipStream_t stream) {
    (void)n_in; (void)out_size; (void)ws_size;
    const float* x   = (const float*)d_in[0];
    const int*   ei  = (const int*)d_in[1];
    const float* W1  = (const float*)d_in[2];
    const float* a1s = (const float*)d_in[3];
    const float* a1d = (const float*)d_in[4];
    const float* b1  = (const float*)d_in[5];
    const float* W2  = (const float*)d_in[6];
    const float* a2s = (const float*)d_in[7];
    const float* a2d = (const float*)d_in[8];
    const float* b2  = (const float*)d_in[9];
    float* out = (float*)d_out;

    const int N = in_sizes[0] / 128;
    const int E = in_sizes[1] / 2;
    const int* src = ei;
    const int* dst = ei + E;

    char* wp = (char*)d_ws;
    auto alloc = [&](size_t bytes) -> void* {
        void* p = (void*)wp;
        wp += (bytes + 255) & ~(size_t)255;
        return p;
    };
    __half* h1   = (__half*)alloc((size_t)N * 128 * 2);
    __half* act1 = (__half*)alloc((size_t)N * 128 * 2);
    __half* h2   = (__half*)alloc((size_t)N * 64 * 2 + 64 * 256);  // +pad: gemm2 tail reads
    float* al1s = (float*)alloc((size_t)N * 8 * 4);
    float* al1d = (float*)alloc((size_t)N * 8 * 4);
    float* al2s = (float*)alloc((size_t)N * 4);
    float* al2d = (float*)alloc((size_t)N * 4);
    int* deg      = (int*)alloc((size_t)N * 4);
    int* rowstart = (int*)alloc((size_t)(N + 1) * 4);
    int* cursor   = (int*)alloc((size_t)N * 4);
    int* esrc     = (int*)alloc((size_t)E * 4);
    int* blocksum = (int*)alloc(256 * 4);
    _Float16* W1t = (_Float16*)alloc(144 * 128 * 2);
    _Float16* W2t = (_Float16*)alloc(80 * 128 * 2);

    const int nbScan = (N + 255) / 256;
    const int gridH  = (E + 1023) / 1024;     // hist blocks (first)
    const int gridG1 = (N + 63) / 64;         // 782 gemm1 blocks
    const int gridScat = ((E + 1023) / 1024) * 8;
    const int gridG2 = (N + 63) / 64;
    const int gridAggN = (N + 31) / 32;

    hipMemsetAsync(deg, 0, (size_t)N * 4, stream);

    augw_kernel<<<2, 256, 0, stream>>>(W1, a1s, a1d, W2, a2s, a2d, W1t, W2t);
    gemm1_hist_kernel<<<gridH + gridG1, 256, 0, stream>>>(
        x, W1t, h1, al1s, al1d, N, dst, E, deg, gridH);
    scan1_kernel<<<nbScan, 256, 0, stream>>>(deg, N, rowstart, blocksum);
    scan23_kernel<<<(N + 256) / 256, 256, 0, stream>>>(rowstart, blocksum, nbScan,
                                                       cursor, N, E);
    scatter_kernel<<<gridScat, 256, 0, stream>>>(src, dst, E, N, cursor, esrc);

    agg1_kernel<<<gridAggN, 256, 0, stream>>>(h1, al1s, al1d, rowstart, esrc, b1, act1, N);
    gemm2_kernel<<<gridG2, 256, 0, stream>>>(act1, W2t, h2, al2s, al2d, N);
    agg2_kernel<<<gridAggN, 256, 0, stream>>>(h2, al2s, al2d, rowstart, esrc, b2, out, N);
}

// Round 10
// 283.092 us; speedup vs baseline: 1.0190x; 1.0190x over previous
//
#include <hip/hip_runtime.h>
#include <hip/hip_fp16.h>
#include <math.h>

// ---------------------------------------------------------------------------
// GAT 2-layer forward, N=50000, E=800000 (+N self loops), EMB=128,
// layer1: heads=8, C=16 (concat -> 128), layer2: heads=1, C=64.
// CSR-by-dst build per call, one gather pass per layer, softmax without
// max-subtraction. h1/h2/act1 fp16. GEMMs on MFMA with augmented-weight alpha
// fusion (R9).
// R10: deg/cursor padded to ONE COUNTER PER 64B LINE (stride 16) -- 800k
//      random device atomics previously hit 3125 lines (~256 RMW/line,
//      serialized). hist split from gemm1 for clean attribution.
// ---------------------------------------------------------------------------

typedef _Float16 f16x8 __attribute__((ext_vector_type(8)));
typedef float f32x4 __attribute__((ext_vector_type(4)));

#define PAD 16  // ints per counter slot (64B line)

__global__ __launch_bounds__(256) void hist_kernel(const int* __restrict__ dst, int E,
                                                   int* __restrict__ deg) {
    int i = (blockIdx.x * 256 + threadIdx.x) * 4;
    if (i + 3 < E) {
        int4 d = *(const int4*)(dst + i);
        atomicAdd(&deg[d.x * PAD], 1);
        atomicAdd(&deg[d.y * PAD], 1);
        atomicAdd(&deg[d.z * PAD], 1);
        atomicAdd(&deg[d.w * PAD], 1);
    } else {
        for (int k = i; k < E; k++) atomicAdd(&deg[dst[k] * PAD], 1);
    }
}

__global__ __launch_bounds__(256) void scan1_kernel(const int* __restrict__ deg, int N,
                                                    int* __restrict__ rowstart,
                                                    int* __restrict__ blocksum) {
    __shared__ int tmp[256];
    int t = threadIdx.x;
    int i = blockIdx.x * 256 + t;
    int v = (i < N) ? deg[i * PAD] : 0;
    tmp[t] = v;
    __syncthreads();
    for (int off = 1; off < 256; off <<= 1) {
        int x = (t >= off) ? tmp[t - off] : 0;
        __syncthreads();
        tmp[t] += x;
        __syncthreads();
    }
    if (i < N) rowstart[i] = tmp[t] - v;
    if (t == 255) blocksum[blockIdx.x] = tmp[t];
}

__global__ __launch_bounds__(256) void scan23_kernel(int* __restrict__ rowstart,
                                                     const int* __restrict__ blocksum,
                                                     int nb,
                                                     int* __restrict__ cursor,
                                                     int N, int E) {
    __shared__ int sdata[256];
    int t = threadIdx.x;
    int b = blockIdx.x;
    sdata[t] = (t < nb && t < b) ? blocksum[t] : 0;
    __syncthreads();
#pragma unroll
    for (int off = 128; off > 0; off >>= 1) {
        if (t < off) sdata[t] += sdata[t + off];
        __syncthreads();
    }
    int offset = sdata[0];
    int i = b * 256 + t;
    if (i < N) {
        int v = rowstart[i] + offset;
        rowstart[i] = v;
        cursor[i * PAD] = v;
    } else if (i == N) {
        rowstart[N] = E;
    }
}

// Bucketed scatter: block (blockIdx&7) commits only dst in its 1/8 range of
// nodes -> esrc write lines stay within one XCD's L2. cursor padded 1/line.
__global__ __launch_bounds__(256) void scatter_kernel(const int* __restrict__ src,
                                                      const int* __restrict__ dst,
                                                      int E, int N,
                                                      int* __restrict__ cursor,
                                                      int* __restrict__ esrc) {
    int b = blockIdx.x & 7;
    int chunk = blockIdx.x >> 3;
    int bdiv = (N + 7) >> 3;
    int blo = b * bdiv;
    int bhi = blo + bdiv;
    int base = chunk * 1024 + threadIdx.x;
#pragma unroll
    for (int u = 0; u < 4; u++) {
        int i = base + u * 256;
        if (i < E) {
            int d = dst[i];
            int s = src[i];
            if (d >= blo && d < bhi) {
                int p = atomicAdd(&cursor[d * PAD], 1);
                esrc[p] = s;
            }
        }
    }
}

// Prep: build transposed fp16 augmented weights.
__global__ __launch_bounds__(256) void augw_kernel(const float* __restrict__ W1,
                                                   const float* __restrict__ a1s,
                                                   const float* __restrict__ a1d,
                                                   const float* __restrict__ W2,
                                                   const float* __restrict__ a2s,
                                                   const float* __restrict__ a2d,
                                                   _Float16* __restrict__ W1t,
                                                   _Float16* __restrict__ W2t) {
    int t = threadIdx.x;
    if (blockIdx.x == 0) {
        for (int i = t; i < 144 * 128; i += 256) {
            int c = i >> 7, k = i & 127;
            float v;
            if (c < 128) {
                v = W1[k * 128 + c];
            } else if (c < 136) {
                int h = c - 128; v = 0.f;
#pragma unroll
                for (int j = 0; j < 16; j++) v += W1[k * 128 + h * 16 + j] * a1s[h * 16 + j];
            } else {
                int h = c - 136; v = 0.f;
#pragma unroll
                for (int j = 0; j < 16; j++) v += W1[k * 128 + h * 16 + j] * a1d[h * 16 + j];
            }
            W1t[c * 128 + k] = (_Float16)v;
        }
    } else {
        for (int i = t; i < 80 * 128; i += 256) {
            int c = i >> 7, k = i & 127;
            float v = 0.f;
            if (c < 64) {
                v = W2[k * 64 + c];
            } else if (c == 64) {
                for (int j = 0; j < 64; j++) v += W2[k * 64 + j] * a2s[j];
            } else if (c == 65) {
                for (int j = 0; j < 64; j++) v += W2[k * 64 + j] * a2d[j];
            }
            W2t[c * 128 + k] = (_Float16)v;
        }
    }
}

// MFMA GEMM1: 64 rows x 144 cols per block (4 waves x 16 rows, 9 col-frags).
// x staged fp32->fp16 into LDS; W1t B-frags from global (36KB, L1-resident).
__global__ __launch_bounds__(256) void gemm1_kernel(const float* __restrict__ x,
                                                    const _Float16* __restrict__ W1t,
                                                    __half* __restrict__ h1,
                                                    float* __restrict__ als,
                                                    float* __restrict__ ald, int N) {
    __shared__ _Float16 Xs[64 * 136];  // 17 KB
    int t = threadIdx.x;
    int row0 = blockIdx.x * 64;
    for (int i = t; i < 2048; i += 256) {
        int r = i >> 5, c4 = i & 31;
        int gr = row0 + r;
        float4 v = make_float4(0.f, 0.f, 0.f, 0.f);
        if (gr < N) v = *(const float4*)(x + (size_t)gr * 128 + c4 * 4);
        _Float16* dp = Xs + r * 136 + c4 * 4;
        dp[0] = (_Float16)v.x; dp[1] = (_Float16)v.y;
        dp[2] = (_Float16)v.z; dp[3] = (_Float16)v.w;
    }
    __syncthreads();
    int w = t >> 6, L = t & 63, m = L & 15, quad = L >> 4;
    f32x4 acc[9];
#pragma unroll
    for (int f = 0; f < 9; f++) acc[f] = (f32x4){0.f, 0.f, 0.f, 0.f};
    const _Float16* Arow = Xs + (w * 16 + m) * 136 + quad * 8;
    const _Float16* Brow = W1t + m * 128 + quad * 8;
#pragma unroll
    for (int kt = 0; kt < 4; kt++) {
        f16x8 a = *(const f16x8*)(Arow + kt * 32);
#pragma unroll
        for (int f = 0; f < 9; f++) {
            f16x8 b = *(const f16x8*)(Brow + f * 2048 + kt * 32);
            acc[f] = __builtin_amdgcn_mfma_f32_16x16x32_f16(a, b, acc[f], 0, 0, 0);
        }
    }
    int nbase = row0 + w * 16 + quad * 4;
#pragma unroll
    for (int r = 0; r < 4; r++) {
        int n = nbase + r;
        if (n < N) {
            __half* hrow = h1 + (size_t)n * 128 + m;
#pragma unroll
            for (int f = 0; f < 8; f++) hrow[f * 16] = __float2half(acc[f][r]);
            float v = acc[8][r];
            if (m < 8) als[n * 8 + m] = v;
            else ald[n * 8 + (m - 8)] = v;
        }
    }
}

// Aggregation layer 1, node-per-group: wave = 8 nodes x 8 lanes; lane q owns
// head q's 16 channels; walks its node's edge list privately (no reduction).
__global__ __launch_bounds__(256) void agg1_kernel(const __half* __restrict__ h1,
                                                   const float* __restrict__ als,
                                                   const float* __restrict__ ald,
                                                   const int* __restrict__ rowstart,
                                                   const int* __restrict__ esrc,
                                                   const float* __restrict__ b1,
                                                   __half* __restrict__ act1, int N) {
    int t = threadIdx.x;
    int lane = t & 63;
    int grp = lane >> 3;
    int q = lane & 7;
    int n = blockIdx.x * 32 + (t >> 6) * 8 + grp;
    if (n >= N) return;
    const float4* h1v = (const float4*)h1;
    float adv = ald[n * 8 + q];
    float acc[16];
    float wsum;
    {  // self loop
        float e = als[n * 8 + q] + adv;
        e = (e > 0.f) ? e : 0.2f * e;
        float w = __expf(e);
        wsum = w;
        float4 hv0 = h1v[(size_t)n * 16 + 2 * q];
        float4 hv1 = h1v[(size_t)n * 16 + 2 * q + 1];
        const __half2* p0 = (const __half2*)&hv0;
        const __half2* p1 = (const __half2*)&hv1;
#pragma unroll
        for (int k = 0; k < 4; k++) {
            float2 f = __half22float2(p0[k]);
            acc[2 * k] = w * f.x;
            acc[2 * k + 1] = w * f.y;
        }
#pragma unroll
        for (int k = 0; k < 4; k++) {
            float2 f = __half22float2(p1[k]);
            acc[8 + 2 * k] = w * f.x;
            acc[8 + 2 * k + 1] = w * f.y;
        }
    }
    int beg = rowstart[n], end = rowstart[n + 1];
    for (int j = beg; j < end; j++) {
        int s = esrc[j];
        float e = als[s * 8 + q] + adv;
        e = (e > 0.f) ? e : 0.2f * e;
        float w = __expf(e);
        wsum += w;
        float4 hv0 = h1v[(size_t)s * 16 + 2 * q];
        float4 hv1 = h1v[(size_t)s * 16 + 2 * q + 1];
        const __half2* p0 = (const __half2*)&hv0;
        const __half2* p1 = (const __half2*)&hv1;
#pragma unroll
        for (int k = 0; k < 4; k++) {
            float2 f = __half22float2(p0[k]);
            acc[2 * k] += w * f.x;
            acc[2 * k + 1] += w * f.y;
        }
#pragma unroll
        for (int k = 0; k < 4; k++) {
            float2 f = __half22float2(p1[k]);
            acc[8 + 2 * k] += w * f.x;
            acc[8 + 2 * k + 1] += w * f.y;
        }
    }
    float inv = 1.f / (wsum + 1e-16f);
    const float* bf = b1 + q * 16;
    __align__(16) __half2 po[8];
#pragma unroll
    for (int k = 0; k < 8; k++) {
        float o0 = acc[2 * k] * inv + bf[2 * k];
        float o1 = acc[2 * k + 1] * inv + bf[2 * k + 1];
        o0 = (o0 > 0.f) ? o0 : (__expf(o0) - 1.f);  // ELU
        o1 = (o1 > 0.f) ? o1 : (__expf(o1) - 1.f);
        po[k] = __floats2half2_rn(o0, o1);
    }
    float4* ov = (float4*)(act1 + (size_t)n * 128 + q * 16);
    ov[0] = ((float4*)po)[0];
    ov[1] = ((float4*)po)[1];
}

// MFMA GEMM2: 64 rows x 80 cols per block; A-frags straight from global act1
// (fp16), B-frags from W2t (20KB, L1-resident). No LDS.
__global__ __launch_bounds__(256) void gemm2_kernel(const __half* __restrict__ act1,
                                                    const _Float16* __restrict__ W2t,
                                                    __half* __restrict__ h2,
                                                    float* __restrict__ al2s,
                                                    float* __restrict__ al2d, int N) {
    int t = threadIdx.x;
    int row0 = blockIdx.x * 64;
    int w = t >> 6, L = t & 63, m = L & 15, quad = L >> 4;
    f32x4 acc[5];
#pragma unroll
    for (int f = 0; f < 5; f++) acc[f] = (f32x4){0.f, 0.f, 0.f, 0.f};
    const _Float16* Arow =
        (const _Float16*)act1 + (size_t)(row0 + w * 16 + m) * 128 + quad * 8;
    const _Float16* Brow = W2t + m * 128 + quad * 8;
#pragma unroll
    for (int kt = 0; kt < 4; kt++) {
        f16x8 a = *(const f16x8*)(Arow + kt * 32);
#pragma unroll
        for (int f = 0; f < 5; f++) {
            f16x8 b = *(const f16x8*)(Brow + f * 2048 + kt * 32);
            acc[f] = __builtin_amdgcn_mfma_f32_16x16x32_f16(a, b, acc[f], 0, 0, 0);
        }
    }
    int nbase = row0 + w * 16 + quad * 4;
#pragma unroll
    for (int r = 0; r < 4; r++) {
        int n = nbase + r;
        if (n < N) {
            __half* hrow = h2 + (size_t)n * 64 + m;
#pragma unroll
            for (int f = 0; f < 4; f++) hrow[f * 16] = __float2half(acc[f][r]);
            if (m == 0) al2s[n] = acc[4][r];
            else if (m == 1) al2d[n] = acc[4][r];
        }
    }
}

// Aggregation layer 2, node-per-group: wave = 8 nodes x 8 lanes; lane q owns
// channels 8q..8q+7; walks its node's edge list privately.
__global__ __launch_bounds__(256) void agg2_kernel(const __half* __restrict__ h2,
                                                   const float* __restrict__ al2s,
                                                   const float* __restrict__ al2d,
                                                   const int* __restrict__ rowstart,
                                                   const int* __restrict__ esrc,
                                                   const float* __restrict__ b2,
                                                   float* __restrict__ out, int N) {
    int t = threadIdx.x;
    int lane = t & 63;
    int grp = lane >> 3;
    int q = lane & 7;
    int n = blockIdx.x * 32 + (t >> 6) * 8 + grp;
    if (n >= N) return;
    const float4* h2v = (const float4*)h2;
    float adv = al2d[n];
    float acc[8];
    float wsum;
    {  // self loop
        float e = al2s[n] + adv;
        e = (e > 0.f) ? e : 0.2f * e;
        float w = __expf(e);
        wsum = w;
        float4 hv = h2v[(size_t)n * 8 + q];
        const __half2* hp = (const __half2*)&hv;
#pragma unroll
        for (int k = 0; k < 4; k++) {
            float2 f = __half22float2(hp[k]);
            acc[2 * k] = w * f.x;
            acc[2 * k + 1] = w * f.y;
        }
    }
    int beg = rowstart[n], end = rowstart[n + 1];
    for (int j = beg; j < end; j++) {
        int s = esrc[j];
        float e = al2s[s] + adv;
        e = (e > 0.f) ? e : 0.2f * e;
        float w = __expf(e);
        wsum += w;
        float4 hv = h2v[(size_t)s * 8 + q];
        const __half2* hp = (const __half2*)&hv;
#pragma unroll
        for (int k = 0; k < 4; k++) {
            float2 f = __half22float2(hp[k]);
            acc[2 * k] += w * f.x;
            acc[2 * k + 1] += w * f.y;
        }
    }
    float inv = 1.f / (wsum + 1e-16f);
    const float* bf = b2 + q * 8;
    float4* ov = (float4*)(out + (size_t)n * 64 + q * 8);
    ov[0] = make_float4(acc[0] * inv + bf[0], acc[1] * inv + bf[1],
                        acc[2] * inv + bf[2], acc[3] * inv + bf[3]);
    ov[1] = make_float4(acc[4] * inv + bf[4], acc[5] * inv + bf[5],
                        acc[6] * inv + bf[6], acc[7] * inv + bf[7]);
}

extern "C" void kernel_launch(void* const* d_in, const int* in_sizes, int n_in,
                              void* d_out, int out_size, void* d_ws, size_t ws_size,
                              hipStream_t stream) {
    (void)n_in; (void)out_size; (void)ws_size;
    const float* x   = (const float*)d_in[0];
    const int*   ei  = (const int*)d_in[1];
    const float* W1  = (const float*)d_in[2];
    const float* a1s = (const float*)d_in[3];
    const float* a1d = (const float*)d_in[4];
    const float* b1  = (const float*)d_in[5];
    const float* W2  = (const float*)d_in[6];
    const float* a2s = (const float*)d_in[7];
    const float* a2d = (const float*)d_in[8];
    const float* b2  = (const float*)d_in[9];
    float* out = (float*)d_out;

    const int N = in_sizes[0] / 128;
    const int E = in_sizes[1] / 2;
    const int* src = ei;
    const int* dst = ei + E;

    char* wp = (char*)d_ws;
    auto alloc = [&](size_t bytes) -> void* {
        void* p = (void*)wp;
        wp += (bytes + 255) & ~(size_t)255;
        return p;
    };
    __half* h1   = (__half*)alloc((size_t)N * 128 * 2);
    __half* act1 = (__half*)alloc((size_t)N * 128 * 2);
    __half* h2   = (__half*)alloc((size_t)N * 64 * 2 + 64 * 256);  // +pad for gemm2 tail
    float* al1s = (float*)alloc((size_t)N * 8 * 4);
    float* al1d = (float*)alloc((size_t)N * 8 * 4);
    float* al2s = (float*)alloc((size_t)N * 4);
    float* al2d = (float*)alloc((size_t)N * 4);
    int* deg      = (int*)alloc((size_t)N * PAD * 4);  // 1 counter / 64B line
    int* rowstart = (int*)alloc((size_t)(N + 1) * 4);
    int* cursor   = (int*)alloc((size_t)N * PAD * 4);  // 1 counter / 64B line
    int* esrc     = (int*)alloc((size_t)E * 4);
    int* blocksum = (int*)alloc(256 * 4);
    _Float16* W1t = (_Float16*)alloc(144 * 128 * 2);
    _Float16* W2t = (_Float16*)alloc(80 * 128 * 2);

    const int nbScan = (N + 255) / 256;
    const int gridH  = (E + 1023) / 1024;
    const int gridG1 = (N + 63) / 64;
    const int gridScat = ((E + 1023) / 1024) * 8;
    const int gridG2 = (N + 63) / 64;
    const int gridAggN = (N + 31) / 32;

    hipMemsetAsync(deg, 0, (size_t)N * PAD * 4, stream);

    augw_kernel<<<2, 256, 0, stream>>>(W1, a1s, a1d, W2, a2s, a2d, W1t, W2t);
    hist_kernel<<<gridH, 256, 0, stream>>>(dst, E, deg);
    gemm1_kernel<<<gridG1, 256, 0, stream>>>(x, W1t, h1, al1s, al1d, N);
    scan1_kernel<<<nbScan, 256, 0, stream>>>(deg, N, rowstart, blocksum);
    scan23_kernel<<<(N + 256) / 256, 256, 0, stream>>>(rowstart, blocksum, nbScan,
                                                       cursor, N, E);
    scatter_kernel<<<gridScat, 256, 0, stream>>>(src, dst, E, N, cursor, esrc);

    agg1_kernel<<<gridAggN, 256, 0, stream>>>(h1, al1s, al1d, rowstart, esrc, b1, act1, N);
    gemm2_kernel<<<gridG2, 256, 0, stream>>>(act1, W2t, h2, al2s, al2d, N);
    agg2_kernel<<<gridAggN, 256, 0, stream>>>(h2, al2s, al2d, rowstart, esrc, b2, out, N);
}